// Round 10
// baseline (30164.114 us; speedup 1.0000x reference)
//
#include <hip/hip_runtime.h>
#include <hip/hip_bf16.h>
#include <hip/hip_fp16.h>
#include <cstdint>
#include <cstddef>

#define B_  16
#define S_  1024
#define DIN 128
#define H_  256
#define G4  1024
#define GD  256
#define CD  17
#define E_  524288
#define N_  16384

typedef _Float16 f16;

__device__ __forceinline__ float sigf(float x) { return 1.0f / (1.0f + __expf(-x)); }
__device__ __forceinline__ float tanhfast(float x) { return 1.0f - 2.0f / (__expf(2.0f * x) + 1.0f); }

// ---------------------------------------------------------------------------
// sentinel (fp32 now)
// ---------------------------------------------------------------------------
__global__ void sentinel_kernel(float* out, float v) {
    out[blockIdx.x * 256 + threadIdx.x] = v;
}

// ---------------------------------------------------------------------------
// CSR build (edge_index: planar int32, src=ei[0..E), dst=ei[E..2E))
// ---------------------------------------------------------------------------
__global__ void count_kernel(const int* __restrict__ ei, int* __restrict__ cnt) {
    int i = blockIdx.x * 256 + threadIdx.x;
    atomicAdd(&cnt[ei[E_ + i]], 1);
}

__global__ void scan_kernel(const int* __restrict__ cnt, int* __restrict__ offs) {
    __shared__ int sums[1024];
    const int t = threadIdx.x;
    int loc[16];
    int s = 0;
    const int base = t * 16;
#pragma unroll
    for (int i = 0; i < 16; i++) { loc[i] = cnt[base + i]; s += loc[i]; }
    sums[t] = s;
    __syncthreads();
    for (int d = 1; d < 1024; d <<= 1) {
        int v = 0;
        if (t >= d) v = sums[t - d];
        __syncthreads();
        if (t >= d) sums[t] += v;
        __syncthreads();
    }
    int ex = (t == 0) ? 0 : sums[t - 1];
#pragma unroll
    for (int i = 0; i < 16; i++) { offs[base + i] = ex; ex += loc[i]; }
    if (t == 1023) offs[N_] = ex;
}

__global__ void fill_kernel(const int* __restrict__ ei, const int* __restrict__ offs,
                            int* __restrict__ cursor, int* __restrict__ csr) {
    int i = blockIdx.x * 256 + threadIdx.x;
    int dv = ei[E_ + i];
    int p = atomicAdd(&cursor[dv], 1);
    csr[offs[dv] + p] = ei[i];
}

__global__ void inv_kernel(const int* __restrict__ cnt, float* __restrict__ invd) {
    int n = blockIdx.x * 256 + threadIdx.x;
    invd[n] = rsqrtf((float)(cnt[n] + 1));
}

// ---------------------------------------------------------------------------
// xg precompute
// ---------------------------------------------------------------------------
__global__ __launch_bounds__(256, 1)
void xg_kernel(const float* __restrict__ x, const float* __restrict__ wih,
               const float* __restrict__ bih, const float* __restrict__ bhh,
               f16* __restrict__ xg) {
    __shared__ float4 xs[256];
    const int tid = threadIdx.x;
    const int gb = blockIdx.x & 3, sc = blockIdx.x >> 2;
    const int row = gb * 256 + tid;
    float wr[128];
#pragma unroll
    for (int k = 0; k < 128; k++) wr[k] = wih[(size_t)row * DIN + k];
    const float bias = bih[row] + bhh[row];

    for (int g = 0; g < 64; ++g) {
        const int pg0 = sc * 512 + g * 8;
        {
            const int q = tid >> 5, f4 = tid & 31;
            const int pg = pg0 + q;
            const int b = pg >> 10, s = pg & 1023;
            xs[tid] = ((const float4*)x)[(size_t)(b * S_ + s) * 32 + f4];
        }
        __syncthreads();
        for (int q = 0; q < 8; q++) {
            float acc = bias;
#pragma unroll
            for (int k = 0; k < 32; k++) {
                float4 v = xs[q * 32 + k];
                acc = fmaf(v.x, wr[4 * k + 0], acc);
                acc = fmaf(v.y, wr[4 * k + 1], acc);
                acc = fmaf(v.z, wr[4 * k + 2], acc);
                acc = fmaf(v.w, wr[4 * k + 3], acc);
            }
            const int pg = pg0 + q;
            const int b = pg >> 10, s = pg & 1023;
            xg[(size_t)(b * S_ + s) * G4 + row] = (f16)acc;
        }
        __syncthreads();
    }
}

// ---------------------------------------------------------------------------
// naive fp32 LSTM (canonical semantics, r7-verified)
// ---------------------------------------------------------------------------
__global__ __launch_bounds__(256)
void lstm_naive_kernel(const f16* __restrict__ xg,
                       const float* __restrict__ whh_f, const float* __restrict__ whh_r,
                       f16* __restrict__ nodes) {
    __shared__ __align__(16) float hA[256], hB[256];
    const int u = threadIdx.x;
    const int d = blockIdx.x >> 4, b = blockIdx.x & 15;
    const float* __restrict__ whh = d ? whh_r : whh_f;
    const float4* __restrict__ wi4 = (const float4*)(whh + (size_t)u * H_);
    const float4* __restrict__ wf4 = (const float4*)(whh + (size_t)(H_ + u) * H_);
    const float4* __restrict__ wg4 = (const float4*)(whh + (size_t)(2 * H_ + u) * H_);
    const float4* __restrict__ wo4 = (const float4*)(whh + (size_t)(3 * H_ + u) * H_);

    hA[u] = 0.f;
    hB[u] = 0.f;
    __syncthreads();

    float c_st = 0.f;
    const f16* __restrict__ xgb = xg + ((size_t)(d * B_ + b)) * S_ * G4;
    f16* __restrict__ nb = nodes + (size_t)b * S_ * 512 + d * H_;

    for (int si = 0; si < S_; ++si) {
        const int s = d ? (S_ - 1 - si) : si;
        const float4* __restrict__ hc = (const float4*)((si & 1) ? hB : hA);
        float* __restrict__ hn = (si & 1) ? hA : hB;

        const f16* xr = xgb + (size_t)s * G4 + u;
        float ai = (float)xr[0];
        float af = (float)xr[256];
        float ag = (float)xr[512];
        float ao = (float)xr[768];

#pragma unroll 4
        for (int k4 = 0; k4 < 64; ++k4) {
            const float4 hv = hc[k4];
            const float4 wia = wi4[k4];
            const float4 wfa = wf4[k4];
            const float4 wga = wg4[k4];
            const float4 woa = wo4[k4];
            ai = fmaf(wia.x, hv.x, ai); ai = fmaf(wia.y, hv.y, ai);
            ai = fmaf(wia.z, hv.z, ai); ai = fmaf(wia.w, hv.w, ai);
            af = fmaf(wfa.x, hv.x, af); af = fmaf(wfa.y, hv.y, af);
            af = fmaf(wfa.z, hv.z, af); af = fmaf(wfa.w, hv.w, af);
            ag = fmaf(wga.x, hv.x, ag); ag = fmaf(wga.y, hv.y, ag);
            ag = fmaf(wga.z, hv.z, ag); ag = fmaf(wga.w, hv.w, ag);
            ao = fmaf(woa.x, hv.x, ao); ao = fmaf(woa.y, hv.y, ao);
            ao = fmaf(woa.z, hv.z, ao); ao = fmaf(woa.w, hv.w, ao);
        }

        const float ig = sigf(ai);
        const float fg = sigf(af);
        const float gt = tanhfast(ag);
        const float og = sigf(ao);
        c_st = fg * c_st + ig * gt;
        const float h = og * tanhfast(c_st);

        hn[u] = h;
        nb[(size_t)s * 512 + u] = (f16)h;
        __syncthreads();
    }
}

// ---------------------------------------------------------------------------
// GEMM: C[N][256] = A[N][K] @ W[K][256]
// ---------------------------------------------------------------------------
template <int K, typename TA>
__global__ __launch_bounds__(256)
void gemm_kernel(const TA* __restrict__ A, const float* __restrict__ W,
                 float* __restrict__ C) {
    __shared__ float at[32][17];
    const int j = threadIdx.x;
    const int r0 = blockIdx.x * 16;
    float acc[16];
#pragma unroll
    for (int r = 0; r < 16; r++) acc[r] = 0.f;

    for (int kc = 0; kc < K; kc += 32) {
        __syncthreads();
        {
            const int i = threadIdx.x;
            const int k = i & 31, r = i >> 5;
            at[k][r]     = (float)A[(size_t)(r0 + r) * K + kc + k];
            at[k][r + 8] = (float)A[(size_t)(r0 + r + 8) * K + kc + k];
        }
        __syncthreads();
#pragma unroll
        for (int k = 0; k < 32; k++) {
            const float wv = W[(size_t)(kc + k) * GD + j];
#pragma unroll
            for (int r = 0; r < 16; r++) acc[r] = fmaf(at[k][r], wv, acc[r]);
        }
    }
#pragma unroll
    for (int r = 0; r < 16; r++) C[(size_t)(r0 + r) * GD + j] = acc[r];
}

// ---------------------------------------------------------------------------
// GCN aggregation
// ---------------------------------------------------------------------------
__global__ __launch_bounds__(256)
void gather_kernel(const float* __restrict__ Hm, const int* __restrict__ csr,
                   const int* __restrict__ offs, const float* __restrict__ inv,
                   const float* __restrict__ bias, float* __restrict__ Out) {
    const int wid = threadIdx.x >> 6, lane = threadIdx.x & 63;
    const int n = blockIdx.x * 4 + wid;
    const float invn = inv[n];
    const float4* __restrict__ H4 = (const float4*)Hm;

    float4 v = H4[(size_t)n * 64 + lane];
    const float sw = invn * invn;
    float ax = v.x * sw, ay = v.y * sw, az = v.z * sw, aw = v.w * sw;

    const int e0 = offs[n], e1 = offs[n + 1];
    for (int e = e0; e < e1; ++e) {
        const int src = csr[e];
        const float w = inv[src] * invn;
        float4 hv = H4[(size_t)src * 64 + lane];
        ax = fmaf(hv.x, w, ax);
        ay = fmaf(hv.y, w, ay);
        az = fmaf(hv.z, w, az);
        aw = fmaf(hv.w, w, aw);
    }
    const float4 bv = ((const float4*)bias)[lane];
    float4 o;
    o.x = fmaxf(ax + bv.x, 0.f);
    o.y = fmaxf(ay + bv.y, 0.f);
    o.z = fmaxf(az + bv.z, 0.f);
    o.w = fmaxf(aw + bv.w, 0.f);
    ((float4*)Out)[(size_t)n * 64 + lane] = o;
}

// ---------------------------------------------------------------------------
// classifier: logits[n][c] = g2[n,:].Wc[:,c] + bc[c]  -- FLOAT32 OUTPUT
// ---------------------------------------------------------------------------
__global__ __launch_bounds__(256)
void cls_kernel(const float* __restrict__ g2, const float* __restrict__ Wc,
                const float* __restrict__ bc, float* __restrict__ out) {
    const int idx = blockIdx.x * 256 + threadIdx.x;
    if (idx >= N_ * CD) return;
    const int n = idx / CD, c = idx % CD;
    const float* __restrict__ row = g2 + (size_t)n * GD;
    float a0 = bc[c], a1 = 0.f, a2 = 0.f, a3 = 0.f;
    for (int k = 0; k < GD; k += 4) {
        a0 = fmaf(row[k + 0], Wc[(size_t)(k + 0) * CD + c], a0);
        a1 = fmaf(row[k + 1], Wc[(size_t)(k + 1) * CD + c], a1);
        a2 = fmaf(row[k + 2], Wc[(size_t)(k + 2) * CD + c], a2);
        a3 = fmaf(row[k + 3], Wc[(size_t)(k + 3) * CD + c], a3);
    }
    out[idx] = (a0 + a1) + (a2 + a3);
}

// ---------------------------------------------------------------------------
extern "C" void kernel_launch(void* const* d_in, const int* in_sizes, int n_in,
                              void* d_out, int out_size, void* d_ws, size_t ws_size,
                              hipStream_t stream) {
    const float* x     = (const float*)d_in[0];
    const int*   ei    = (const int*)d_in[1];
    const float* wih_f = (const float*)d_in[2];
    const float* whh_f = (const float*)d_in[3];
    const float* bih_f = (const float*)d_in[4];
    const float* bhh_f = (const float*)d_in[5];
    const float* wih_r = (const float*)d_in[6];
    const float* whh_r = (const float*)d_in[7];
    const float* bih_r = (const float*)d_in[8];
    const float* bhh_r = (const float*)d_in[9];
    const float* W1    = (const float*)d_in[10];
    const float* b1    = (const float*)d_in[11];
    const float* W2    = (const float*)d_in[12];
    const float* b2    = (const float*)d_in[13];
    const float* Wc    = (const float*)d_in[14];
    const float* bc    = (const float*)d_in[15];
    float* out = (float*)d_out;   // reference output dtype is float32
    (void)out_size;

    static const int EXP_SIZES[16] = {
        2097152, 1048576, 131072, 262144, 1024, 1024,
        131072, 262144, 1024, 1024, 131072, 256, 65536, 256, 4352, 17
    };
    if (n_in != 16) { sentinel_kernel<<<4, 256, 0, stream>>>(out, 3.5e6f); return; }
    for (int i = 0; i < 16; ++i) {
        if (in_sizes[i] != EXP_SIZES[i]) {
            sentinel_kernel<<<4, 256, 0, stream>>>(out, 1.0e6f + (float)(i + 1) * 1.0e5f);
            return;
        }
    }

    const size_t XG_B    = (size_t)2 * B_ * S_ * G4 * sizeof(f16);
    const size_t NODES_B = (size_t)N_ * 512 * sizeof(f16);
    const size_t MAT_B   = (size_t)N_ * GD * sizeof(float);
    char* ws = (char*)d_ws;
    size_t off = 0;
    auto alloc = [&](size_t bytes) -> char* {
        char* p = ws + off;
        off = (off + bytes + 255) & ~(size_t)255;
        return p;
    };
    f16*   xg     = (f16*)  alloc(XG_B);
    f16*   nodes  = (f16*)  alloc(NODES_B);
    int*   cnt    = (int*)  alloc((size_t)N_ * 4);
    float* invd   = (float*)alloc((size_t)N_ * 4);
    int*   offs   = (int*)  alloc((size_t)(N_ + 1) * 4);
    int*   cursor = (int*)  alloc((size_t)N_ * 4);
    int*   csr    = (int*)  alloc((size_t)E_ * 4);
    const size_t NEED = off;
    float* h1 = (float*)(ws + 0);
    float* g1 = (float*)(ws + MAT_B);
    float* g2 = (float*)(ws + 2 * MAT_B);

    if (ws_size < NEED) {
        sentinel_kernel<<<4, 256, 0, stream>>>(out, 1.0e6f + 1000.0f * (float)(ws_size >> 20));
        return;
    }

    hipMemsetAsync(cnt, 0, (size_t)N_ * 4, stream);
    hipMemsetAsync(cursor, 0, (size_t)N_ * 4, stream);

    count_kernel<<<E_ / 256, 256, 0, stream>>>(ei, cnt);
    scan_kernel<<<1, 1024, 0, stream>>>(cnt, offs);
    fill_kernel<<<E_ / 256, 256, 0, stream>>>(ei, offs, cursor, csr);
    inv_kernel<<<N_ / 256, 256, 0, stream>>>(cnt, invd);

    xg_kernel<<<128, 256, 0, stream>>>(x, wih_f, bih_f, bhh_f, xg);
    xg_kernel<<<128, 256, 0, stream>>>(x, wih_r, bih_r, bhh_r, xg + (size_t)B_ * S_ * G4);

    lstm_naive_kernel<<<32, 256, 0, stream>>>(xg, whh_f, whh_r, nodes);

    gemm_kernel<512, f16><<<N_ / 16, 256, 0, stream>>>(nodes, W1, h1);
    gather_kernel<<<N_ / 4, 256, 0, stream>>>(h1, csr, offs, invd, b1, g1);
    gemm_kernel<256, float><<<N_ / 16, 256, 0, stream>>>(g1, W2, h1);
    gather_kernel<<<N_ / 4, 256, 0, stream>>>(h1, csr, offs, invd, b2, g2);
    cls_kernel<<<(N_ * CD + 255) / 256, 256, 0, stream>>>(g2, Wc, bc, out);
}

// Round 11
// 3255.445 us; speedup vs baseline: 9.2657x; 9.2657x over previous
//
#include <hip/hip_runtime.h>
#include <hip/hip_bf16.h>
#include <hip/hip_fp16.h>
#include <cstdint>
#include <cstddef>

#define B_  16
#define S_  1024
#define DIN 128
#define H_  256
#define G4  1024
#define GD  256
#define CD  17
#define E_  524288
#define N_  16384

typedef _Float16 f16;
typedef _Float16 f16x2 __attribute__((ext_vector_type(2)));
typedef _Float16 f16x8 __attribute__((ext_vector_type(8)));

#define DOT2(a, b, c) __builtin_amdgcn_fdot2((a), (b), (c), false)

__device__ __forceinline__ float sigf(float x) { return 1.0f / (1.0f + __expf(-x)); }
__device__ __forceinline__ float tanhfast(float x) { return 1.0f - 2.0f / (__expf(2.0f * x) + 1.0f); }

// ---------------------------------------------------------------------------
__global__ void sentinel_kernel(float* out, float v) {
    out[blockIdx.x * 256 + threadIdx.x] = v;
}

// ---------------------------------------------------------------------------
// CSR build (edge_index: planar int32, src=ei[0..E), dst=ei[E..2E))
// ---------------------------------------------------------------------------
__global__ void count_kernel(const int* __restrict__ ei, int* __restrict__ cnt) {
    int i = blockIdx.x * 256 + threadIdx.x;
    atomicAdd(&cnt[ei[E_ + i]], 1);
}

__global__ void scan_kernel(const int* __restrict__ cnt, int* __restrict__ offs) {
    __shared__ int sums[1024];
    const int t = threadIdx.x;
    int loc[16];
    int s = 0;
    const int base = t * 16;
#pragma unroll
    for (int i = 0; i < 16; i++) { loc[i] = cnt[base + i]; s += loc[i]; }
    sums[t] = s;
    __syncthreads();
    for (int d = 1; d < 1024; d <<= 1) {
        int v = 0;
        if (t >= d) v = sums[t - d];
        __syncthreads();
        if (t >= d) sums[t] += v;
        __syncthreads();
    }
    int ex = (t == 0) ? 0 : sums[t - 1];
#pragma unroll
    for (int i = 0; i < 16; i++) { offs[base + i] = ex; ex += loc[i]; }
    if (t == 1023) offs[N_] = ex;
}

__global__ void fill_kernel(const int* __restrict__ ei, const int* __restrict__ offs,
                            int* __restrict__ cursor, int* __restrict__ csr) {
    int i = blockIdx.x * 256 + threadIdx.x;
    int dv = ei[E_ + i];
    int p = atomicAdd(&cursor[dv], 1);
    csr[offs[dv] + p] = ei[i];
}

__global__ void inv_kernel(const int* __restrict__ cnt, float* __restrict__ invd) {
    int n = blockIdx.x * 256 + threadIdx.x;
    invd[n] = rsqrtf((float)(cnt[n] + 1));
}

// ---------------------------------------------------------------------------
// xg precompute
// ---------------------------------------------------------------------------
__global__ __launch_bounds__(256, 1)
void xg_kernel(const float* __restrict__ x, const float* __restrict__ wih,
               const float* __restrict__ bih, const float* __restrict__ bhh,
               f16* __restrict__ xg) {
    __shared__ float4 xs[256];
    const int tid = threadIdx.x;
    const int gb = blockIdx.x & 3, sc = blockIdx.x >> 2;
    const int row = gb * 256 + tid;
    float wr[128];
#pragma unroll
    for (int k = 0; k < 128; k++) wr[k] = wih[(size_t)row * DIN + k];
    const float bias = bih[row] + bhh[row];

    for (int g = 0; g < 64; ++g) {
        const int pg0 = sc * 512 + g * 8;
        {
            const int q = tid >> 5, f4 = tid & 31;
            const int pg = pg0 + q;
            const int b = pg >> 10, s = pg & 1023;
            xs[tid] = ((const float4*)x)[(size_t)(b * S_ + s) * 32 + f4];
        }
        __syncthreads();
        for (int q = 0; q < 8; q++) {
            float acc = bias;
#pragma unroll
            for (int k = 0; k < 32; k++) {
                float4 v = xs[q * 32 + k];
                acc = fmaf(v.x, wr[4 * k + 0], acc);
                acc = fmaf(v.y, wr[4 * k + 1], acc);
                acc = fmaf(v.z, wr[4 * k + 2], acc);
                acc = fmaf(v.w, wr[4 * k + 3], acc);
            }
            const int pg = pg0 + q;
            const int b = pg >> 10, s = pg & 1023;
            xg[(size_t)(b * S_ + s) * G4 + row] = (f16)acc;
        }
        __syncthreads();
    }
}

// ---------------------------------------------------------------------------
// OPTIMIZED LSTM (r3 design, verified == naive via r3/r4 bit-identical runs):
// 32 blocks = (dir, batch). 512 threads = (unit u, K-half kh).
// i/f/o weight half-rows in 192 VGPRs (f16x2), g half-rows in swizzled LDS,
// h as f16 in double-buffered LDS, fp32 accumulation via v_dot2_f32_f16.
// ---------------------------------------------------------------------------
__global__ __launch_bounds__(512, 2)
void lstm_kernel(const f16* __restrict__ xg,  // [2][B][S][1024]
                 const float* __restrict__ whh_f, const float* __restrict__ whh_r,
                 f16* __restrict__ nodes)     // [N][512] f16
{
    __shared__ __align__(16) f16x2 gw[256 * 2 * 64];  // 128 KB g-rows, swizzled
    __shared__ __align__(16) f16 hbuf[2][256];        // h double buffer

    const int t = threadIdx.x;
    const int u = t >> 1, kh = t & 1;
    const int u7 = u & 7;
    const int d = blockIdx.x >> 4, b = blockIdx.x & 15;
    const float* __restrict__ whh = d ? whh_r : whh_f;

    // i,f,o half-rows -> registers as packed f16 pairs
    f16x2 wr[3][64];
    {
        const int rws[3] = {u, 256 + u, 768 + u};
#pragma unroll
        for (int r = 0; r < 3; r++) {
            const float* src = whh + (size_t)rws[r] * H_ + kh * 128;
#pragma unroll
            for (int c = 0; c < 64; c++) {
                f16x2 w; w[0] = (f16)src[2 * c]; w[1] = (f16)src[2 * c + 1];
                wr[r][c] = w;
            }
        }
    }
    // g half-row -> LDS with XOR swizzle on 16B slots
    {
        const float* src = whh + (size_t)(512 + u) * H_ + kh * 128;
        f16x2* dst = gw + (u * 2 + kh) * 64;
#pragma unroll
        for (int lw = 0; lw < 64; ++lw) {
            int phys = (((lw >> 2) ^ u7) << 2) | (lw & 3);
            f16x2 w; w[0] = (f16)src[2 * lw]; w[1] = (f16)src[2 * lw + 1];
            dst[phys] = w;
        }
    }
    if (t < 256) { hbuf[0][t] = (f16)0.f; hbuf[1][t] = (f16)0.f; }
    __syncthreads();

    float c_st = 0.f;
    const f16* xgb = xg + ((size_t)(d * B_ + b)) * S_ * G4;
    f16* nb = nodes + (size_t)b * S_ * 512 + d * H_;

    for (int si = 0; si < S_; ++si) {
        const int s = d ? (S_ - 1 - si) : si;
        const int cur = si & 1;

        const f16* xr = xgb + (size_t)s * G4 + u;
        const float xi = (float)xr[0];
        const float xf = (float)xr[256];
        const float xg_ = (float)xr[512];
        const float xo = (float)xr[768];

        float a0 = 0.f, a1 = 0.f, a2 = 0.f, a3 = 0.f;
        float a4 = 0.f, a5 = 0.f, a6 = 0.f, a7 = 0.f;
        const f16x8* hp = (const f16x8*)&hbuf[cur][kh * 128];
        const f16x8* gp = (const f16x8*)(gw + (u * 2 + kh) * 64);

#pragma unroll
        for (int c = 0; c < 4; c++) {
#pragma unroll
            for (int j = 0; j < 4; j++) {
                f16x8 hv = hp[c * 4 + j];
                f16x8 gv = gp[(c * 4 + j) ^ u7];
#pragma unroll
                for (int p = 0; p < 4; p++) {
                    f16x2 h2; h2[0] = hv[2 * p]; h2[1] = hv[2 * p + 1];
                    f16x2 g2; g2[0] = gv[2 * p]; g2[1] = gv[2 * p + 1];
                    const int w = c * 16 + j * 4 + p;
                    if (p & 1) {
                        a1 = DOT2(h2, wr[0][w], a1);
                        a3 = DOT2(h2, wr[1][w], a3);
                        a5 = DOT2(h2, wr[2][w], a5);
                        a7 = DOT2(h2, g2, a7);
                    } else {
                        a0 = DOT2(h2, wr[0][w], a0);
                        a2 = DOT2(h2, wr[1][w], a2);
                        a4 = DOT2(h2, wr[2][w], a4);
                        a6 = DOT2(h2, g2, a6);
                    }
                }
            }
        }
        float ti = a0 + a1, tf = a2 + a3, to = a4 + a5, tg = a6 + a7;
        ti += __shfl_xor(ti, 1);
        tf += __shfl_xor(tf, 1);
        to += __shfl_xor(to, 1);
        tg += __shfl_xor(tg, 1);

        const float ig = sigf(xi + ti);
        const float fg = sigf(xf + tf);
        const float gt = tanhfast(xg_ + tg);
        const float og = sigf(xo + to);
        c_st = fg * c_st + ig * gt;
        const float h = og * tanhfast(c_st);
        const f16 hfv = (f16)h;

        if (kh == 0) {
            hbuf[cur ^ 1][u] = hfv;
            nb[(size_t)s * 512 + u] = hfv;
        }
        __syncthreads();
    }
}

// ---------------------------------------------------------------------------
// GEMM: C[N][256] = A[N][K] @ W[K][256]
// ---------------------------------------------------------------------------
template <int K, typename TA>
__global__ __launch_bounds__(256)
void gemm_kernel(const TA* __restrict__ A, const float* __restrict__ W,
                 float* __restrict__ C) {
    __shared__ float at[32][17];
    const int j = threadIdx.x;
    const int r0 = blockIdx.x * 16;
    float acc[16];
#pragma unroll
    for (int r = 0; r < 16; r++) acc[r] = 0.f;

    for (int kc = 0; kc < K; kc += 32) {
        __syncthreads();
        {
            const int i = threadIdx.x;
            const int k = i & 31, r = i >> 5;
            at[k][r]     = (float)A[(size_t)(r0 + r) * K + kc + k];
            at[k][r + 8] = (float)A[(size_t)(r0 + r + 8) * K + kc + k];
        }
        __syncthreads();
#pragma unroll
        for (int k = 0; k < 32; k++) {
            const float wv = W[(size_t)(kc + k) * GD + j];
#pragma unroll
            for (int r = 0; r < 16; r++) acc[r] = fmaf(at[k][r], wv, acc[r]);
        }
    }
#pragma unroll
    for (int r = 0; r < 16; r++) C[(size_t)(r0 + r) * GD + j] = acc[r];
}

// ---------------------------------------------------------------------------
// GCN aggregation
// ---------------------------------------------------------------------------
__global__ __launch_bounds__(256)
void gather_kernel(const float* __restrict__ Hm, const int* __restrict__ csr,
                   const int* __restrict__ offs, const float* __restrict__ inv,
                   const float* __restrict__ bias, float* __restrict__ Out) {
    const int wid = threadIdx.x >> 6, lane = threadIdx.x & 63;
    const int n = blockIdx.x * 4 + wid;
    const float invn = inv[n];
    const float4* __restrict__ H4 = (const float4*)Hm;

    float4 v = H4[(size_t)n * 64 + lane];
    const float sw = invn * invn;
    float ax = v.x * sw, ay = v.y * sw, az = v.z * sw, aw = v.w * sw;

    const int e0 = offs[n], e1 = offs[n + 1];
    for (int e = e0; e < e1; ++e) {
        const int src = csr[e];
        const float w = inv[src] * invn;
        float4 hv = H4[(size_t)src * 64 + lane];
        ax = fmaf(hv.x, w, ax);
        ay = fmaf(hv.y, w, ay);
        az = fmaf(hv.z, w, az);
        aw = fmaf(hv.w, w, aw);
    }
    const float4 bv = ((const float4*)bias)[lane];
    float4 o;
    o.x = fmaxf(ax + bv.x, 0.f);
    o.y = fmaxf(ay + bv.y, 0.f);
    o.z = fmaxf(az + bv.z, 0.f);
    o.w = fmaxf(aw + bv.w, 0.f);
    ((float4*)Out)[(size_t)n * 64 + lane] = o;
}

// ---------------------------------------------------------------------------
// classifier: float32 output
// ---------------------------------------------------------------------------
__global__ __launch_bounds__(256)
void cls_kernel(const float* __restrict__ g2, const float* __restrict__ Wc,
                const float* __restrict__ bc, float* __restrict__ out) {
    const int idx = blockIdx.x * 256 + threadIdx.x;
    if (idx >= N_ * CD) return;
    const int n = idx / CD, c = idx % CD;
    const float* __restrict__ row = g2 + (size_t)n * GD;
    float a0 = bc[c], a1 = 0.f, a2 = 0.f, a3 = 0.f;
    for (int k = 0; k < GD; k += 4) {
        a0 = fmaf(row[k + 0], Wc[(size_t)(k + 0) * CD + c], a0);
        a1 = fmaf(row[k + 1], Wc[(size_t)(k + 1) * CD + c], a1);
        a2 = fmaf(row[k + 2], Wc[(size_t)(k + 2) * CD + c], a2);
        a3 = fmaf(row[k + 3], Wc[(size_t)(k + 3) * CD + c], a3);
    }
    out[idx] = (a0 + a1) + (a2 + a3);
}

// ---------------------------------------------------------------------------
extern "C" void kernel_launch(void* const* d_in, const int* in_sizes, int n_in,
                              void* d_out, int out_size, void* d_ws, size_t ws_size,
                              hipStream_t stream) {
    const float* x     = (const float*)d_in[0];
    const int*   ei    = (const int*)d_in[1];
    const float* wih_f = (const float*)d_in[2];
    const float* whh_f = (const float*)d_in[3];
    const float* bih_f = (const float*)d_in[4];
    const float* bhh_f = (const float*)d_in[5];
    const float* wih_r = (const float*)d_in[6];
    const float* whh_r = (const float*)d_in[7];
    const float* bih_r = (const float*)d_in[8];
    const float* bhh_r = (const float*)d_in[9];
    const float* W1    = (const float*)d_in[10];
    const float* b1    = (const float*)d_in[11];
    const float* W2    = (const float*)d_in[12];
    const float* b2    = (const float*)d_in[13];
    const float* Wc    = (const float*)d_in[14];
    const float* bc    = (const float*)d_in[15];
    float* out = (float*)d_out;
    (void)out_size;

    static const int EXP_SIZES[16] = {
        2097152, 1048576, 131072, 262144, 1024, 1024,
        131072, 262144, 1024, 1024, 131072, 256, 65536, 256, 4352, 17
    };
    if (n_in != 16) { sentinel_kernel<<<4, 256, 0, stream>>>(out, 3.5e6f); return; }
    for (int i = 0; i < 16; ++i) {
        if (in_sizes[i] != EXP_SIZES[i]) {
            sentinel_kernel<<<4, 256, 0, stream>>>(out, 1.0e6f + (float)(i + 1) * 1.0e5f);
            return;
        }
    }

    const size_t XG_B    = (size_t)2 * B_ * S_ * G4 * sizeof(f16);
    const size_t NODES_B = (size_t)N_ * 512 * sizeof(f16);
    const size_t MAT_B   = (size_t)N_ * GD * sizeof(float);
    char* ws = (char*)d_ws;
    size_t off = 0;
    auto alloc = [&](size_t bytes) -> char* {
        char* p = ws + off;
        off = (off + bytes + 255) & ~(size_t)255;
        return p;
    };
    f16*   xg     = (f16*)  alloc(XG_B);
    f16*   nodes  = (f16*)  alloc(NODES_B);
    int*   cnt    = (int*)  alloc((size_t)N_ * 4);
    float* invd   = (float*)alloc((size_t)N_ * 4);
    int*   offs   = (int*)  alloc((size_t)(N_ + 1) * 4);
    int*   cursor = (int*)  alloc((size_t)N_ * 4);
    int*   csr    = (int*)  alloc((size_t)E_ * 4);
    const size_t NEED = off;
    float* h1 = (float*)(ws + 0);
    float* g1 = (float*)(ws + MAT_B);
    float* g2 = (float*)(ws + 2 * MAT_B);

    if (ws_size < NEED) {
        sentinel_kernel<<<4, 256, 0, stream>>>(out, 1.0e6f + 1000.0f * (float)(ws_size >> 20));
        return;
    }

    hipMemsetAsync(cnt, 0, (size_t)N_ * 4, stream);
    hipMemsetAsync(cursor, 0, (size_t)N_ * 4, stream);

    count_kernel<<<E_ / 256, 256, 0, stream>>>(ei, cnt);
    scan_kernel<<<1, 1024, 0, stream>>>(cnt, offs);
    fill_kernel<<<E_ / 256, 256, 0, stream>>>(ei, offs, cursor, csr);
    inv_kernel<<<N_ / 256, 256, 0, stream>>>(cnt, invd);

    xg_kernel<<<128, 256, 0, stream>>>(x, wih_f, bih_f, bhh_f, xg);
    xg_kernel<<<128, 256, 0, stream>>>(x, wih_r, bih_r, bhh_r, xg + (size_t)B_ * S_ * G4);

    lstm_kernel<<<32, 512, 0, stream>>>(xg, whh_f, whh_r, nodes);

    gemm_kernel<512, f16><<<N_ / 16, 256, 0, stream>>>(nodes, W1, h1);
    gather_kernel<<<N_ / 4, 256, 0, stream>>>(h1, csr, offs, invd, b1, g1);
    gemm_kernel<256, float><<<N_ / 16, 256, 0, stream>>>(g1, W2, h1);
    gather_kernel<<<N_ / 4, 256, 0, stream>>>(h1, csr, offs, invd, b2, g2);
    cls_kernel<<<(N_ * CD + 255) / 256, 256, 0, stream>>>(g2, Wc, bc, out);
}

// Round 12
// 2360.144 us; speedup vs baseline: 12.7806x; 1.3793x over previous
//
#include <hip/hip_runtime.h>
#include <hip/hip_bf16.h>
#include <hip/hip_fp16.h>
#include <cstdint>
#include <cstddef>

#define B_  16
#define S_  1024
#define DIN 128
#define H_  256
#define G4  1024
#define GD  256
#define CD  17
#define E_  524288
#define N_  16384

typedef _Float16 f16;
typedef _Float16 f16x2 __attribute__((ext_vector_type(2)));
typedef _Float16 f16x8 __attribute__((ext_vector_type(8)));
typedef float    f32x4 __attribute__((ext_vector_type(4)));

#define DOT2(a, b, c) __builtin_amdgcn_fdot2((a), (b), (c), false)

__device__ __forceinline__ float sigf(float x) { return 1.0f / (1.0f + __expf(-x)); }
__device__ __forceinline__ float tanhfast(float x) { return 1.0f - 2.0f / (__expf(2.0f * x) + 1.0f); }

// ---------------------------------------------------------------------------
__global__ void sentinel_kernel(float* out, float v) {
    out[blockIdx.x * 256 + threadIdx.x] = v;
}

// ---------------------------------------------------------------------------
// CSR build (edge_index: planar int32)
// ---------------------------------------------------------------------------
__global__ void count_kernel(const int* __restrict__ ei, int* __restrict__ cnt) {
    int i = blockIdx.x * 256 + threadIdx.x;
    atomicAdd(&cnt[ei[E_ + i]], 1);
}

__global__ void scan_kernel(const int* __restrict__ cnt, int* __restrict__ offs) {
    __shared__ int sums[1024];
    const int t = threadIdx.x;
    int loc[16];
    int s = 0;
    const int base = t * 16;
#pragma unroll
    for (int i = 0; i < 16; i++) { loc[i] = cnt[base + i]; s += loc[i]; }
    sums[t] = s;
    __syncthreads();
    for (int d = 1; d < 1024; d <<= 1) {
        int v = 0;
        if (t >= d) v = sums[t - d];
        __syncthreads();
        if (t >= d) sums[t] += v;
        __syncthreads();
    }
    int ex = (t == 0) ? 0 : sums[t - 1];
#pragma unroll
    for (int i = 0; i < 16; i++) { offs[base + i] = ex; ex += loc[i]; }
    if (t == 1023) offs[N_] = ex;
}

__global__ void fill_kernel(const int* __restrict__ ei, const int* __restrict__ offs,
                            int* __restrict__ cursor, int* __restrict__ csr) {
    int i = blockIdx.x * 256 + threadIdx.x;
    int dv = ei[E_ + i];
    int p = atomicAdd(&cursor[dv], 1);
    csr[offs[dv] + p] = ei[i];
}

__global__ void inv_kernel(const int* __restrict__ cnt, float* __restrict__ invd) {
    int n = blockIdx.x * 256 + threadIdx.x;
    invd[n] = rsqrtf((float)(cnt[n] + 1));
}

// ---------------------------------------------------------------------------
// conversions / weight prep
// ---------------------------------------------------------------------------
__global__ void cvt16_kernel(const float* __restrict__ src, f16* __restrict__ dst, int n) {
    int i = blockIdx.x * 256 + threadIdx.x;
    if (i < n) dst[i] = (f16)src[i];
}

__global__ void bias_comb_kernel(const float* __restrict__ a, const float* __restrict__ b,
                                 float* __restrict__ o) {
    int i = blockIdx.x * 256 + threadIdx.x;
    o[i] = a[i] + b[i];
}

// W [K][256] f32 -> hi/lo [256][K] f16 (transposed, residual-split)
template <int K>
__global__ void wsplit_kernel(const float* __restrict__ W, f16* __restrict__ hi,
                              f16* __restrict__ lo) {
    int idx = blockIdx.x * 256 + threadIdx.x;  // over K*256
    int k = idx >> 8, n = idx & 255;
    float v = W[idx];
    f16 h = (f16)v;
    hi[(size_t)n * K + k] = h;
    lo[(size_t)n * K + k] = (f16)(v - (float)h);
}

// ---------------------------------------------------------------------------
// MFMA GEMM: C[M][ldc] (+bias) = A[M][K](f16) @ BT[N][K](f16,transposed)
// block = 4 waves, M-tile 64 (16/wave), N-chunk 256 via blockIdx.y.
// mfma_f32_16x16x32_f16; layouts: A m=lane&15,k=(lane>>4)*8+j;
// B n=lane&15, same k; C/D col=lane&15,row=(lane>>4)*4+r (m89-verified).
// RESID: second MFMA with BTlo residual (recovers fp32 weight precision).
// ---------------------------------------------------------------------------
template <int K, bool BIAS, bool RESID, typename OutT>
__global__ __launch_bounds__(256)
void mgemm_kernel(const f16* __restrict__ A, const f16* __restrict__ BT,
                  const f16* __restrict__ BTlo, const float* __restrict__ bias,
                  OutT* __restrict__ C, int ldc)
{
    const int wv = threadIdx.x >> 6, lane = threadIdx.x & 63;
    const int m0 = blockIdx.x * 64 + wv * 16;
    const int n0 = blockIdx.y * 256;
    const int rw = lane & 15, kq = lane >> 4;
    f32x4 acc[16];
#pragma unroll
    for (int t = 0; t < 16; ++t) acc[t] = (f32x4){0.f, 0.f, 0.f, 0.f};

    const f16* __restrict__ Ap = A + (size_t)(m0 + rw) * K + kq * 8;
    for (int k0 = 0; k0 < K; k0 += 32) {
        const f16x8 a = *(const f16x8*)(Ap + k0);
#pragma unroll
        for (int t = 0; t < 16; ++t) {
            const size_t boff = (size_t)(n0 + t * 16 + rw) * K + k0 + kq * 8;
            acc[t] = __builtin_amdgcn_mfma_f32_16x16x32_f16(a, *(const f16x8*)(BT + boff), acc[t], 0, 0, 0);
            if constexpr (RESID) {
                acc[t] = __builtin_amdgcn_mfma_f32_16x16x32_f16(a, *(const f16x8*)(BTlo + boff), acc[t], 0, 0, 0);
            }
        }
    }
    const int orow = m0 + kq * 4;
#pragma unroll
    for (int t = 0; t < 16; ++t) {
        const int col = n0 + t * 16 + rw;
        float bv = 0.f;
        if constexpr (BIAS) bv = bias[col];
#pragma unroll
        for (int r = 0; r < 4; ++r) {
            C[(size_t)(orow + r) * ldc + col] = (OutT)(acc[t][r] + bv);
        }
    }
}

// ---------------------------------------------------------------------------
// LSTM (unchanged from r11 — control anchor)
// ---------------------------------------------------------------------------
__global__ __launch_bounds__(512, 2)
void lstm_kernel(const f16* __restrict__ xg,
                 const float* __restrict__ whh_f, const float* __restrict__ whh_r,
                 f16* __restrict__ nodes)
{
    __shared__ __align__(16) f16x2 gw[256 * 2 * 64];
    __shared__ __align__(16) f16 hbuf[2][256];

    const int t = threadIdx.x;
    const int u = t >> 1, kh = t & 1;
    const int u7 = u & 7;
    const int d = blockIdx.x >> 4, b = blockIdx.x & 15;
    const float* __restrict__ whh = d ? whh_r : whh_f;

    f16x2 wr[3][64];
    {
        const int rws[3] = {u, 256 + u, 768 + u};
#pragma unroll
        for (int r = 0; r < 3; r++) {
            const float* src = whh + (size_t)rws[r] * H_ + kh * 128;
#pragma unroll
            for (int c = 0; c < 64; c++) {
                f16x2 w; w[0] = (f16)src[2 * c]; w[1] = (f16)src[2 * c + 1];
                wr[r][c] = w;
            }
        }
    }
    {
        const float* src = whh + (size_t)(512 + u) * H_ + kh * 128;
        f16x2* dst = gw + (u * 2 + kh) * 64;
#pragma unroll
        for (int lw = 0; lw < 64; ++lw) {
            int phys = (((lw >> 2) ^ u7) << 2) | (lw & 3);
            f16x2 w; w[0] = (f16)src[2 * lw]; w[1] = (f16)src[2 * lw + 1];
            dst[phys] = w;
        }
    }
    if (t < 256) { hbuf[0][t] = (f16)0.f; hbuf[1][t] = (f16)0.f; }
    __syncthreads();

    float c_st = 0.f;
    const f16* xgb = xg + ((size_t)(d * B_ + b)) * S_ * G4;
    f16* nb = nodes + (size_t)b * S_ * 512 + d * H_;

    for (int si = 0; si < S_; ++si) {
        const int s = d ? (S_ - 1 - si) : si;
        const int cur = si & 1;

        const f16* xr = xgb + (size_t)s * G4 + u;
        const float xi = (float)xr[0];
        const float xf = (float)xr[256];
        const float xg_ = (float)xr[512];
        const float xo = (float)xr[768];

        float a0 = 0.f, a1 = 0.f, a2 = 0.f, a3 = 0.f;
        float a4 = 0.f, a5 = 0.f, a6 = 0.f, a7 = 0.f;
        const f16x8* hp = (const f16x8*)&hbuf[cur][kh * 128];
        const f16x8* gp = (const f16x8*)(gw + (u * 2 + kh) * 64);

#pragma unroll
        for (int c = 0; c < 4; c++) {
#pragma unroll
            for (int j = 0; j < 4; j++) {
                f16x8 hv = hp[c * 4 + j];
                f16x8 gv = gp[(c * 4 + j) ^ u7];
#pragma unroll
                for (int p = 0; p < 4; p++) {
                    f16x2 h2; h2[0] = hv[2 * p]; h2[1] = hv[2 * p + 1];
                    f16x2 g2; g2[0] = gv[2 * p]; g2[1] = gv[2 * p + 1];
                    const int w = c * 16 + j * 4 + p;
                    if (p & 1) {
                        a1 = DOT2(h2, wr[0][w], a1);
                        a3 = DOT2(h2, wr[1][w], a3);
                        a5 = DOT2(h2, wr[2][w], a5);
                        a7 = DOT2(h2, g2, a7);
                    } else {
                        a0 = DOT2(h2, wr[0][w], a0);
                        a2 = DOT2(h2, wr[1][w], a2);
                        a4 = DOT2(h2, wr[2][w], a4);
                        a6 = DOT2(h2, g2, a6);
                    }
                }
            }
        }
        float ti = a0 + a1, tf = a2 + a3, to = a4 + a5, tg = a6 + a7;
        ti += __shfl_xor(ti, 1);
        tf += __shfl_xor(tf, 1);
        to += __shfl_xor(to, 1);
        tg += __shfl_xor(tg, 1);

        const float ig = sigf(xi + ti);
        const float fg = sigf(xf + tf);
        const float gt = tanhfast(xg_ + tg);
        const float og = sigf(xo + to);
        c_st = fg * c_st + ig * gt;
        const float h = og * tanhfast(c_st);
        const f16 hfv = (f16)h;

        if (kh == 0) {
            hbuf[cur ^ 1][u] = hfv;
            nb[(size_t)s * 512 + u] = hfv;
        }
        __syncthreads();
    }
}

// ---------------------------------------------------------------------------
// GCN aggregation (output type templated: f16 for g1, f32 for g2)
// ---------------------------------------------------------------------------
template <typename OutT>
__global__ __launch_bounds__(256)
void gather_kernel(const float* __restrict__ Hm, const int* __restrict__ csr,
                   const int* __restrict__ offs, const float* __restrict__ inv,
                   const float* __restrict__ bias, OutT* __restrict__ Out) {
    const int wid = threadIdx.x >> 6, lane = threadIdx.x & 63;
    const int n = blockIdx.x * 4 + wid;
    const float invn = inv[n];
    const float4* __restrict__ H4 = (const float4*)Hm;

    float4 v = H4[(size_t)n * 64 + lane];
    const float sw = invn * invn;
    float ax = v.x * sw, ay = v.y * sw, az = v.z * sw, aw = v.w * sw;

    const int e0 = offs[n], e1 = offs[n + 1];
    for (int e = e0; e < e1; ++e) {
        const int src = csr[e];
        const float w = inv[src] * invn;
        float4 hv = H4[(size_t)src * 64 + lane];
        ax = fmaf(hv.x, w, ax);
        ay = fmaf(hv.y, w, ay);
        az = fmaf(hv.z, w, az);
        aw = fmaf(hv.w, w, aw);
    }
    const float4 bv = ((const float4*)bias)[lane];
    OutT* o = Out + (size_t)n * GD + lane * 4;
    o[0] = (OutT)fmaxf(ax + bv.x, 0.f);
    o[1] = (OutT)fmaxf(ay + bv.y, 0.f);
    o[2] = (OutT)fmaxf(az + bv.z, 0.f);
    o[3] = (OutT)fmaxf(aw + bv.w, 0.f);
}

// ---------------------------------------------------------------------------
// classifier: float32 output
// ---------------------------------------------------------------------------
__global__ __launch_bounds__(256)
void cls_kernel(const float* __restrict__ g2, const float* __restrict__ Wc,
                const float* __restrict__ bc, float* __restrict__ out) {
    const int idx = blockIdx.x * 256 + threadIdx.x;
    if (idx >= N_ * CD) return;
    const int n = idx / CD, c = idx % CD;
    const float* __restrict__ row = g2 + (size_t)n * GD;
    float a0 = bc[c], a1 = 0.f, a2 = 0.f, a3 = 0.f;
    for (int k = 0; k < GD; k += 4) {
        a0 = fmaf(row[k + 0], Wc[(size_t)(k + 0) * CD + c], a0);
        a1 = fmaf(row[k + 1], Wc[(size_t)(k + 1) * CD + c], a1);
        a2 = fmaf(row[k + 2], Wc[(size_t)(k + 2) * CD + c], a2);
        a3 = fmaf(row[k + 3], Wc[(size_t)(k + 3) * CD + c], a3);
    }
    out[idx] = (a0 + a1) + (a2 + a3);
}

// ---------------------------------------------------------------------------
extern "C" void kernel_launch(void* const* d_in, const int* in_sizes, int n_in,
                              void* d_out, int out_size, void* d_ws, size_t ws_size,
                              hipStream_t stream) {
    const float* x     = (const float*)d_in[0];
    const int*   ei    = (const int*)d_in[1];
    const float* wih_f = (const float*)d_in[2];
    const float* whh_f = (const float*)d_in[3];
    const float* bih_f = (const float*)d_in[4];
    const float* bhh_f = (const float*)d_in[5];
    const float* wih_r = (const float*)d_in[6];
    const float* whh_r = (const float*)d_in[7];
    const float* bih_r = (const float*)d_in[8];
    const float* bhh_r = (const float*)d_in[9];
    const float* W1    = (const float*)d_in[10];
    const float* b1    = (const float*)d_in[11];
    const float* W2    = (const float*)d_in[12];
    const float* b2    = (const float*)d_in[13];
    const float* Wc    = (const float*)d_in[14];
    const float* bc    = (const float*)d_in[15];
    float* out = (float*)d_out;
    (void)out_size;

    static const int EXP_SIZES[16] = {
        2097152, 1048576, 131072, 262144, 1024, 1024,
        131072, 262144, 1024, 1024, 131072, 256, 65536, 256, 4352, 17
    };
    if (n_in != 16) { sentinel_kernel<<<4, 256, 0, stream>>>(out, 3.5e6f); return; }
    for (int i = 0; i < 16; ++i) {
        if (in_sizes[i] != EXP_SIZES[i]) {
            sentinel_kernel<<<4, 256, 0, stream>>>(out, 1.0e6f + (float)(i + 1) * 1.0e5f);
            return;
        }
    }

    // ---- workspace (same 86.25 MB footprint proven in r3..r11) ----
    char* ws = (char*)d_ws;
    size_t off = 0;
    auto alloc = [&](size_t bytes) -> char* {
        char* p = ws + off;
        off = (off + bytes + 255) & ~(size_t)255;
        return p;
    };
    f16*   xg     = (f16*)  alloc((size_t)2 * B_ * S_ * G4 * sizeof(f16));  // 67.1 MB
    f16*   nodes  = (f16*)  alloc((size_t)N_ * 512 * sizeof(f16));          // 16.8 MB
    int*   cnt    = (int*)  alloc((size_t)N_ * 4);
    float* invd   = (float*)alloc((size_t)N_ * 4);
    int*   offs   = (int*)  alloc((size_t)(N_ + 1) * 4);
    int*   cursor = (int*)  alloc((size_t)N_ * 4);
    int*   csr    = (int*)  alloc((size_t)E_ * 4);
    const size_t NEED = off;

    // pre-LSTM tenants of the nodes region (dead before lstm writes nodes)
    char* nreg = (char*)nodes;
    f16*   xf16   = (f16*)  (nreg);                       // 4.19 MB
    f16*   wih16f = (f16*)  (nreg + 4300800);             // 262 KB
    f16*   wih16r = (f16*)  (nreg + 4300800 + 270336);
    float* biasf  = (float*)(nreg + 4300800 + 2 * 270336);
    float* biasr  = (float*)(nreg + 4300800 + 2 * 270336 + 8192);

    // post-LSTM tenants of the xg region (xg dead after lstm)
    char* xreg = (char*)xg;
    float* h1 = (float*)(xreg);                            // 16.8 MB
    f16*   g1 = (f16*)  (xreg + 16777216);                 // 8.4 MB
    float* g2 = (float*)(xreg + 16777216 + 8388608);       // 16.8 MB (ends 41.9M)
    f16*   W1Thi = (f16*)(xreg + 50331648);                // 256 KB
    f16*   W1Tlo = (f16*)(xreg + 50331648 + 262144);
    f16*   W2Thi = (f16*)(xreg + 50331648 + 2 * 262144);   // 128 KB
    f16*   W2Tlo = (f16*)(xreg + 50331648 + 2 * 262144 + 131072);

    if (ws_size < NEED) {
        sentinel_kernel<<<4, 256, 0, stream>>>(out, 1.0e6f + 1000.0f * (float)(ws_size >> 20));
        return;
    }

    hipMemsetAsync(cnt, 0, (size_t)N_ * 4, stream);
    hipMemsetAsync(cursor, 0, (size_t)N_ * 4, stream);

    // graph
    count_kernel<<<E_ / 256, 256, 0, stream>>>(ei, cnt);
    scan_kernel<<<1, 1024, 0, stream>>>(cnt, offs);
    fill_kernel<<<E_ / 256, 256, 0, stream>>>(ei, offs, cursor, csr);
    inv_kernel<<<N_ / 256, 256, 0, stream>>>(cnt, invd);

    // input conversions
    cvt16_kernel<<<(2097152 + 255) / 256, 256, 0, stream>>>(x, xf16, 2097152);
    cvt16_kernel<<<(131072 + 255) / 256, 256, 0, stream>>>(wih_f, wih16f, 131072);
    cvt16_kernel<<<(131072 + 255) / 256, 256, 0, stream>>>(wih_r, wih16r, 131072);
    bias_comb_kernel<<<4, 256, 0, stream>>>(bih_f, bhh_f, biasf);
    bias_comb_kernel<<<4, 256, 0, stream>>>(bih_r, bhh_r, biasr);

    // xg = x @ wih^T + bias   (wih is [1024][128] = already [n][k])
    mgemm_kernel<128, true, false, f16><<<dim3(256, 4), 256, 0, stream>>>(
        xf16, wih16f, nullptr, biasf, xg, G4);
    mgemm_kernel<128, true, false, f16><<<dim3(256, 4), 256, 0, stream>>>(
        xf16, wih16r, nullptr, biasr, xg + (size_t)B_ * S_ * G4, G4);

    lstm_kernel<<<32, 512, 0, stream>>>(xg, whh_f, whh_r, nodes);

    // weight prep for GCN gemms (into now-dead xg region)
    wsplit_kernel<512><<<512 * 256 / 256, 256, 0, stream>>>(W1, W1Thi, W1Tlo);
    wsplit_kernel<256><<<256 * 256 / 256, 256, 0, stream>>>(W2, W2Thi, W2Tlo);

    mgemm_kernel<512, false, true, float><<<dim3(256, 1), 256, 0, stream>>>(
        nodes, W1Thi, W1Tlo, nullptr, h1, GD);
    gather_kernel<f16><<<N_ / 4, 256, 0, stream>>>(h1, csr, offs, invd, b1, g1);
    mgemm_kernel<256, false, true, float><<<dim3(256, 1), 256, 0, stream>>>(
        g1, W2Thi, W2Tlo, nullptr, h1, GD);
    gather_kernel<float><<<N_ / 4, 256, 0, stream>>>(h1, csr, offs, invd, b2, g2);
    cls_kernel<<<(N_ * CD + 255) / 256, 256, 0, stream>>>(g2, Wc, bc, out);
}